// Round 1
// baseline (8177.065 us; speedup 1.0000x reference)
//
#include <hip/hip_runtime.h>
#include <math.h>

#define DDIM 512
#define TLEN 128
#define RB   4
#define NWG  (256 / RB)
#define VDIM 32000
#define BDIM 256

// ---------------- workgroup-wide 4-lane-packed sum over 512 threads ----------
__device__ __forceinline__ float4 wgsum4(float4 v, float4* red) {
  const int lane = threadIdx.x & 63;
  const int wid  = threadIdx.x >> 6;
  #pragma unroll
  for (int off = 32; off >= 1; off >>= 1) {
    v.x += __shfl_xor(v.x, off);
    v.y += __shfl_xor(v.y, off);
    v.z += __shfl_xor(v.z, off);
    v.w += __shfl_xor(v.w, off);
  }
  __syncthreads();                 // protect red[] from previous use
  if (lane == 0) red[wid] = v;
  __syncthreads();
  float4 t = red[0];
  #pragma unroll
  for (int w = 1; w < 8; ++w) {
    t.x += red[w].x; t.y += red[w].y; t.z += red[w].z; t.w += red[w].w;
  }
  return t;
}

__device__ __forceinline__ void wgsum4a(float v[RB], float4* red) {
  float4 t = wgsum4(make_float4(v[0], v[1], v[2], v[3]), red);
  v[0] = t.x; v[1] = t.y; v[2] = t.z; v[3] = t.w;
}

// ---------------- recurrence: one WG = RB batch rows, thread = column --------
__global__ __launch_bounds__(DDIM) void attractor_recurrence(
    const int*   __restrict__ tokens,
    const float* __restrict__ embed,
    const float* __restrict__ diffusion,   // symmetric [512][512]
    const float* __restrict__ gamma_p,
    const float* __restrict__ beta_p,
    float*       __restrict__ comb_out)    // [256][512]
{
  const int i    = threadIdx.x;   // column 0..511
  const int row0 = blockIdx.x * RB;

  __shared__ float4 s_pack[DDIM];   // (fast_r0..r3)[j]
  __shared__ float4 red[8];

  const float gamma = gamma_p[0];
  const float beta  = beta_p[0];
  const float bss   = beta * 0.5f;          // beta * SIGNAL_SCALE

  float fast[RB], slow[RB];
  #pragma unroll
  for (int r = 0; r < RB; ++r) { fast[r] = 0.f; slow[r] = 0.f; }
  s_pack[i] = make_float4(0.f, 0.f, 0.f, 0.f);
  __syncthreads();

  for (int t = 0; t < TLEN; ++t) {
    // ---- embed gather + layernorm + unit-normalize -> base -----------------
    float ev[RB];
    #pragma unroll
    for (int r = 0; r < RB; ++r) {
      const int tok = tokens[(row0 + r) * TLEN + t];
      ev[r] = embed[(size_t)tok * DDIM + i];
    }
    float mu[RB];
    #pragma unroll
    for (int r = 0; r < RB; ++r) mu[r] = ev[r];
    wgsum4a(mu, red);
    float dv[RB], vr[RB];
    #pragma unroll
    for (int r = 0; r < RB; ++r) {
      mu[r] *= (1.f / DDIM);
      dv[r]  = ev[r] - mu[r];
      vr[r]  = dv[r] * dv[r];
    }
    wgsum4a(vr, red);
    float base[RB];
    #pragma unroll
    for (int r = 0; r < RB; ++r) {
      const float var  = vr[r] * (1.f / DDIM);
      const float inv  = rsqrtf(var + 1e-5f);
      const float y    = dv[r] * inv;
      // ||y||^2 = D*var/(var+eps)
      const float n    = sqrtf((float)DDIM * var / (var + 1e-5f));
      base[r] = y / fmaxf(n, 1e-12f);
    }

    // ---- context vector + signal ------------------------------------------
    float fn2[RB], cn2[RB], cb[RB];
    #pragma unroll
    for (int r = 0; r < RB; ++r) {
      cb[r]  = fast[r] + 0.3f * slow[r];     // W_FAST*fast + W_SLOW*slow
      fn2[r] = fast[r] * fast[r];
      cn2[r] = cb[r] * cb[r];
    }
    wgsum4a(fn2, red);
    wgsum4a(cn2, red);
    float sig[RB], sg2[RB];
    #pragma unroll
    for (int r = 0; r < RB; ++r) {
      const float fn = sqrtf(fn2[r]);
      const float cn = sqrtf(cn2[r]);
      const float fd = fast[r] / (fn + 1e-6f);
      const float cd = cb[r]   / (cn + 1e-6f);
      const float ctx = (fn > 1e-8f) ? fd : ((cn > 1e-8f) ? cd : 0.f);
      sig[r] = base[r] + gamma * ctx;
      sg2[r] = sig[r] * sig[r];
    }
    wgsum4a(sg2, red);
    #pragma unroll
    for (int r = 0; r < RB; ++r) sig[r] /= (sqrtf(sg2[r]) + 1e-6f);

    // ---- 4 conv steps ------------------------------------------------------
    #pragma unroll 1
    for (int k = 0; k < 4; ++k) {
      float m[RB];
      #pragma unroll
      for (int r = 0; r < RB; ++r) m[r] = fast[r];
      wgsum4a(m, red);                       // sum; mean applied below

      // matvec: drift_r[i] = sum_j A[j*512+i] * s_r[j]   (A symmetric)
      float acc[RB] = {0.f, 0.f, 0.f, 0.f};
      #pragma unroll 8
      for (int j = 0; j < DDIM; ++j) {
        const float a = diffusion[j * DDIM + i];   // coalesced across threads
        const float4 sj = s_pack[j];               // LDS broadcast
        acc[0] = fmaf(a, sj.x, acc[0]);
        acc[1] = fmaf(a, sj.y, acc[1]);
        acc[2] = fmaf(a, sj.z, acc[2]);
        acc[3] = fmaf(a, sj.w, acc[3]);
      }

      float sp[RB], n2[RB];
      #pragma unroll
      for (int r = 0; r < RB; ++r) {
        const float s     = fast[r];
        const float c     = s - m[r] * (1.f / DDIM);
        const float drift = acc[r] + 0.008f * tanhf(c) + bss * sig[r] - 0.1f * s;
        sp[r] = s + 0.04f * drift;           // nan_to_num / clip are no-ops here
        n2[r] = sp[r] * sp[r];
      }
      wgsum4a(n2, red);                      // also fences matvec reads of s_pack
      #pragma unroll
      for (int r = 0; r < RB; ++r) fast[r] = sp[r] / (sqrtf(n2[r]) + 1e-8f);
      s_pack[i] = make_float4(fast[0], fast[1], fast[2], fast[3]);
      __syncthreads();
    }

    // ---- slow update -------------------------------------------------------
    float slw[RB], sn2[RB];
    #pragma unroll
    for (int r = 0; r < RB; ++r) {
      slw[r] = 0.95f * slow[r] + 0.05f * fast[r];
      sn2[r] = slw[r] * slw[r];
    }
    wgsum4a(sn2, red);
    #pragma unroll
    for (int r = 0; r < RB; ++r) {
      const float n = sqrtf(sn2[r]);
      slow[r] = (n > 0.5f) ? slw[r] * (0.5f / (n + 1e-12f)) : slw[r];
    }
  }

  #pragma unroll
  for (int r = 0; r < RB; ++r)
    comb_out[(size_t)(row0 + r) * DDIM + i] = fast[r] + 0.3f * slow[r];
}

// ---------------- readout GEMM: out[b][v] = sum_d comb[b][d]*W[v][d] ---------
#define KC  32
#define LDT 132   // padded LDS row stride (dwords), 16B-aligned rows

__global__ __launch_bounds__(256) void logits_gemm(
    const float* __restrict__ comb,   // [256][512]
    const float* __restrict__ W,      // [32000][512]
    float*       __restrict__ out)    // [256][32000]
{
  __shared__ float wt[KC * LDT];
  __shared__ float ct[KC * LDT];

  const int tid = threadIdx.x;
  const int v0  = blockIdx.x * 128;
  const int b0  = blockIdx.y * 128;
  const int tb  = tid >> 4;   // 0..15 (b subtile)
  const int tv  = tid & 15;   // 0..15 (v subtile)

  float acc[8][8];
  #pragma unroll
  for (int a = 0; a < 8; ++a)
    #pragma unroll
    for (int b = 0; b < 8; ++b) acc[a][b] = 0.f;

  for (int kk = 0; kk < DDIM; kk += KC) {
    #pragma unroll
    for (int it = 0; it < 4; ++it) {
      const int l4  = tid + it * 256;      // 0..1023
      const int row = l4 >> 3;             // 0..127
      const int k4  = (l4 & 7) << 2;       // 0,4,..,28
      const float4 gw = *(const float4*)&W[(size_t)(v0 + row) * DDIM + kk + k4];
      const float4 gc = *(const float4*)&comb[(size_t)(b0 + row) * DDIM + kk + k4];
      wt[(k4 + 0) * LDT + row] = gw.x;
      wt[(k4 + 1) * LDT + row] = gw.y;
      wt[(k4 + 2) * LDT + row] = gw.z;
      wt[(k4 + 3) * LDT + row] = gw.w;
      ct[(k4 + 0) * LDT + row] = gc.x;
      ct[(k4 + 1) * LDT + row] = gc.y;
      ct[(k4 + 2) * LDT + row] = gc.z;
      ct[(k4 + 3) * LDT + row] = gc.w;
    }
    __syncthreads();

    for (int kx = 0; kx < KC; ++kx) {
      const float4 c0 = *(const float4*)&ct[kx * LDT + tb * 8];
      const float4 c1 = *(const float4*)&ct[kx * LDT + tb * 8 + 4];
      const float4 w0 = *(const float4*)&wt[kx * LDT + tv * 8];
      const float4 w1 = *(const float4*)&wt[kx * LDT + tv * 8 + 4];
      const float cw[8] = {c0.x, c0.y, c0.z, c0.w, c1.x, c1.y, c1.z, c1.w};
      const float wv[8] = {w0.x, w0.y, w0.z, w0.w, w1.x, w1.y, w1.z, w1.w};
      #pragma unroll
      for (int ib = 0; ib < 8; ++ib)
        #pragma unroll
        for (int iv = 0; iv < 8; ++iv)
          acc[ib][iv] = fmaf(cw[ib], wv[iv], acc[ib][iv]);
    }
    __syncthreads();
  }

  #pragma unroll
  for (int ib = 0; ib < 8; ++ib) {
    const size_t base = (size_t)(b0 + tb * 8 + ib) * VDIM + v0 + tv * 8;
    float4 o0 = make_float4(acc[ib][0], acc[ib][1], acc[ib][2], acc[ib][3]);
    float4 o1 = make_float4(acc[ib][4], acc[ib][5], acc[ib][6], acc[ib][7]);
    *(float4*)&out[base]     = o0;
    *(float4*)&out[base + 4] = o1;
  }
}

extern "C" void kernel_launch(void* const* d_in, const int* in_sizes, int n_in,
                              void* d_out, int out_size, void* d_ws, size_t ws_size,
                              hipStream_t stream) {
  const int*   tokens    = (const int*)d_in[0];
  const float* embed     = (const float*)d_in[1];
  const float* readout_w = (const float*)d_in[2];
  const float* diffusion = (const float*)d_in[3];
  const float* gamma_p   = (const float*)d_in[4];
  const float* beta_p    = (const float*)d_in[5];

  float* comb = (float*)d_ws;              // [256][512] f32 = 512 KB
  float* out  = (float*)d_out;

  hipLaunchKernelGGL(attractor_recurrence, dim3(NWG), dim3(DDIM), 0, stream,
                     tokens, embed, diffusion, gamma_p, beta_p, comb);
  hipLaunchKernelGGL(logits_gemm, dim3(VDIM / 128, BDIM / 128), dim3(256), 0, stream,
                     comb, readout_w, out);
}

// Round 2
// 7339.017 us; speedup vs baseline: 1.1142x; 1.1142x over previous
//
#include <hip/hip_runtime.h>
#include <math.h>

#define DDIM 512
#define TLEN 128
#define RB   4
#define NWG  (256 / RB)   // 64 workgroups
#define VDIM 32000
#define BDIM 256

typedef _Float16 h2 __attribute__((ext_vector_type(2)));

// ---------------- pack A into f16 pairs along j ------------------------------
// pk[j2*512 + i] = ( A[2*j2][i] , A[2*j2+1][i] )  as 2xf16 in one dword
__global__ __launch_bounds__(256) void pack_diffusion(
    const float* __restrict__ A, unsigned int* __restrict__ pk)
{
  const int idx = blockIdx.x * 256 + threadIdx.x;   // 0 .. 131071
  const int i  = idx & 511;
  const int j2 = idx >> 9;
  const float a0 = A[(size_t)(2 * j2)     * DDIM + i];
  const float a1 = A[(size_t)(2 * j2 + 1) * DDIM + i];
  h2 p;
  p.x = (_Float16)a0;
  p.y = (_Float16)a1;
  pk[idx] = __builtin_bit_cast(unsigned int, p);
}

// ---------------- workgroup-wide 4-lane-packed sum over 512 threads ----------
__device__ __forceinline__ float4 wgsum4(float4 v, float4* red) {
  const int lane = threadIdx.x & 63;
  const int wid  = threadIdx.x >> 6;
  #pragma unroll
  for (int off = 32; off >= 1; off >>= 1) {
    v.x += __shfl_xor(v.x, off);
    v.y += __shfl_xor(v.y, off);
    v.z += __shfl_xor(v.z, off);
    v.w += __shfl_xor(v.w, off);
  }
  __syncthreads();                 // protect red[] from previous use
  if (lane == 0) red[wid] = v;
  __syncthreads();
  float4 t = red[0];
  #pragma unroll
  for (int w = 1; w < 8; ++w) {
    t.x += red[w].x; t.y += red[w].y; t.z += red[w].z; t.w += red[w].w;
  }
  return t;
}

__device__ __forceinline__ void wgsum4a(float v[RB], float4* red) {
  float4 t = wgsum4(make_float4(v[0], v[1], v[2], v[3]), red);
  v[0] = t.x; v[1] = t.y; v[2] = t.z; v[3] = t.w;
}

// dot2: acc += a.x*b.x + a.y*b.y  (f16 inputs, f32 accumulate)
__device__ __forceinline__ float dot2(unsigned int a, unsigned int b, float acc) {
#if __has_builtin(__builtin_amdgcn_fdot2)
  return __builtin_amdgcn_fdot2(__builtin_bit_cast(h2, a),
                                __builtin_bit_cast(h2, b), acc, false);
#else
  const h2 ha = __builtin_bit_cast(h2, a);
  const h2 hb = __builtin_bit_cast(h2, b);
  acc = fmaf((float)ha.x, (float)hb.x, acc);
  acc = fmaf((float)ha.y, (float)hb.y, acc);
  return acc;
#endif
}

// ---------------- recurrence: one WG = RB batch rows -------------------------
__global__ __launch_bounds__(DDIM) void attractor_recurrence(
    const int*          __restrict__ tokens,
    const float*        __restrict__ embed,
    const unsigned int* __restrict__ Apk,      // packed f16, [256][512] dwords
    const float*        __restrict__ gamma_p,
    const float*        __restrict__ beta_p,
    float*              __restrict__ comb_out) // [256][512]
{
  const int i    = threadIdx.x;     // owned column 0..511
  const int i4   = threadIdx.x & 127;  // matvec col group (cols i4*4..i4*4+3)
  const int jg   = threadIdx.x >> 7;   // j-quarter 0..3
  const int row0 = blockIdx.x * RB;

  __shared__ uint4  s2p[256];          // packed f16 state pairs; .x...w = rows 0..3
  __shared__ float4 red4[4][DDIM];     // jg-split partial sums (32 KB)
  __shared__ float4 red[8];

  const float gamma = gamma_p[0];
  const float beta  = beta_p[0];
  const float bss   = beta * 0.5f;     // beta * SIGNAL_SCALE

  float fast[RB], slow[RB];
  #pragma unroll
  for (int r = 0; r < RB; ++r) { fast[r] = 0.f; slow[r] = 0.f; }
  if (i < 256) s2p[i] = make_uint4(0u, 0u, 0u, 0u);
  __syncthreads();

  for (int t = 0; t < TLEN; ++t) {
    // ---- embed gather + layernorm + unit-normalize -> base -----------------
    float ev[RB];
    #pragma unroll
    for (int r = 0; r < RB; ++r) {
      const int tok = tokens[(row0 + r) * TLEN + t];
      ev[r] = embed[(size_t)tok * DDIM + i];
    }
    float mu[RB];
    #pragma unroll
    for (int r = 0; r < RB; ++r) mu[r] = ev[r];
    wgsum4a(mu, red);
    float dv[RB], vr[RB];
    #pragma unroll
    for (int r = 0; r < RB; ++r) {
      mu[r] *= (1.f / DDIM);
      dv[r]  = ev[r] - mu[r];
      vr[r]  = dv[r] * dv[r];
    }
    wgsum4a(vr, red);
    float base[RB];
    #pragma unroll
    for (int r = 0; r < RB; ++r) {
      const float var = vr[r] * (1.f / DDIM);
      const float inv = rsqrtf(var + 1e-5f);
      const float y   = dv[r] * inv;
      const float n   = sqrtf((float)DDIM * var / (var + 1e-5f)); // ||y||
      base[r] = y / fmaxf(n, 1e-12f);
    }

    // ---- context vector + signal ------------------------------------------
    float fn2[RB], cn2[RB], cb[RB];
    #pragma unroll
    for (int r = 0; r < RB; ++r) {
      cb[r]  = fast[r] + 0.3f * slow[r];
      fn2[r] = fast[r] * fast[r];
      cn2[r] = cb[r] * cb[r];
    }
    wgsum4a(fn2, red);
    wgsum4a(cn2, red);
    float sig[RB], sg2[RB];
    #pragma unroll
    for (int r = 0; r < RB; ++r) {
      const float fn = sqrtf(fn2[r]);
      const float cn = sqrtf(cn2[r]);
      const float fd = fast[r] / (fn + 1e-6f);
      const float cd = cb[r]   / (cn + 1e-6f);
      const float ctx = (fn > 1e-8f) ? fd : ((cn > 1e-8f) ? cd : 0.f);
      sig[r] = base[r] + gamma * ctx;
      sg2[r] = sig[r] * sig[r];
    }
    wgsum4a(sg2, red);
    #pragma unroll
    for (int r = 0; r < RB; ++r) sig[r] /= (sqrtf(sg2[r]) + 1e-6f);

    // ---- 4 conv steps ------------------------------------------------------
    #pragma unroll 1
    for (int k = 0; k < 4; ++k) {
      float m[RB];
      #pragma unroll
      for (int r = 0; r < RB; ++r) m[r] = fast[r];
      wgsum4a(m, red);                 // sum; /D applied below

      // matvec partials: this thread covers cols i4*4..+3, j-pairs j2 = jg..255 step 4
      float acc[RB][4];
      #pragma unroll
      for (int r = 0; r < RB; ++r)
        #pragma unroll
        for (int c = 0; c < 4; ++c) acc[r][c] = 0.f;

      const unsigned int* ap = Apk + (size_t)jg * DDIM + i4 * 4;
      #pragma unroll 4
      for (int j2 = jg; j2 < 256; j2 += 4) {
        const uint4 a = *(const uint4*)ap;      // 4 cols of this j-pair
        const uint4 s = s2p[j2];                // rows 0..3 (LDS broadcast)
        ap += 4 * DDIM;
        const unsigned int av[4] = {a.x, a.y, a.z, a.w};
        const unsigned int sv[4] = {s.x, s.y, s.z, s.w};
        #pragma unroll
        for (int r = 0; r < RB; ++r)
          #pragma unroll
          for (int c = 0; c < 4; ++c)
            acc[r][c] = dot2(av[c], sv[r], acc[r][c]);
      }

      __syncthreads();   // everyone done with s2p reads & prior red4 use
      #pragma unroll
      for (int c = 0; c < 4; ++c)
        red4[jg][i4 * 4 + c] = make_float4(acc[0][c], acc[1][c], acc[2][c], acc[3][c]);
      __syncthreads();
      float4 d0 = red4[0][i];
      const float4 d1 = red4[1][i];
      const float4 d2 = red4[2][i];
      const float4 d3 = red4[3][i];
      d0.x += d1.x + d2.x + d3.x;
      d0.y += d1.y + d2.y + d3.y;
      d0.z += d1.z + d2.z + d3.z;
      d0.w += d1.w + d2.w + d3.w;
      const float mv[RB] = {d0.x, d0.y, d0.z, d0.w};

      float sp[RB], n2[RB];
      #pragma unroll
      for (int r = 0; r < RB; ++r) {
        const float s     = fast[r];
        const float c     = s - m[r] * (1.f / DDIM);
        const float drift = mv[r] + 0.008f * tanhf(c) + bss * sig[r] - 0.1f * s;
        sp[r] = s + 0.04f * drift;       // nan_to_num / clip are no-ops here
        n2[r] = sp[r] * sp[r];
      }
      wgsum4a(n2, red);                  // internal syncs fence red4 reuse
      unsigned int pr[RB];
      #pragma unroll
      for (int r = 0; r < RB; ++r) {
        fast[r] = sp[r] / (sqrtf(n2[r]) + 1e-8f);
        const float nb = __shfl_xor(fast[r], 1);
        h2 p; p.x = (_Float16)fast[r]; p.y = (_Float16)nb;  // valid for even i
        pr[r] = __builtin_bit_cast(unsigned int, p);
      }
      if ((i & 1) == 0) s2p[i >> 1] = make_uint4(pr[0], pr[1], pr[2], pr[3]);
      __syncthreads();
    }

    // ---- slow update -------------------------------------------------------
    float slw[RB], sn2[RB];
    #pragma unroll
    for (int r = 0; r < RB; ++r) {
      slw[r] = 0.95f * slow[r] + 0.05f * fast[r];
      sn2[r] = slw[r] * slw[r];
    }
    wgsum4a(sn2, red);
    #pragma unroll
    for (int r = 0; r < RB; ++r) {
      const float n = sqrtf(sn2[r]);
      slow[r] = (n > 0.5f) ? slw[r] * (0.5f / (n + 1e-12f)) : slw[r];
    }
  }

  #pragma unroll
  for (int r = 0; r < RB; ++r)
    comb_out[(size_t)(row0 + r) * DDIM + i] = fast[r] + 0.3f * slow[r];
}

// ---------------- readout GEMM: out[b][v] = sum_d comb[b][d]*W[v][d] ---------
#define KC  32
#define LDT 132   // padded LDS row stride (dwords)

__global__ __launch_bounds__(256) void logits_gemm(
    const float* __restrict__ comb,   // [256][512]
    const float* __restrict__ W,      // [32000][512]
    float*       __restrict__ out)    // [256][32000]
{
  __shared__ float wt[KC * LDT];
  __shared__ float ct[KC * LDT];

  const int tid = threadIdx.x;
  const int v0  = blockIdx.x * 128;
  const int b0  = blockIdx.y * 128;
  const int tb  = tid >> 4;   // 0..15
  const int tv  = tid & 15;   // 0..15

  float acc[8][8];
  #pragma unroll
  for (int a = 0; a < 8; ++a)
    #pragma unroll
    for (int b = 0; b < 8; ++b) acc[a][b] = 0.f;

  for (int kk = 0; kk < DDIM; kk += KC) {
    #pragma unroll
    for (int it = 0; it < 4; ++it) {
      const int l4  = tid + it * 256;
      const int row = l4 >> 3;
      const int k4  = (l4 & 7) << 2;
      const float4 gw = *(const float4*)&W[(size_t)(v0 + row) * DDIM + kk + k4];
      const float4 gc = *(const float4*)&comb[(size_t)(b0 + row) * DDIM + kk + k4];
      wt[(k4 + 0) * LDT + row] = gw.x;
      wt[(k4 + 1) * LDT + row] = gw.y;
      wt[(k4 + 2) * LDT + row] = gw.z;
      wt[(k4 + 3) * LDT + row] = gw.w;
      ct[(k4 + 0) * LDT + row] = gc.x;
      ct[(k4 + 1) * LDT + row] = gc.y;
      ct[(k4 + 2) * LDT + row] = gc.z;
      ct[(k4 + 3) * LDT + row] = gc.w;
    }
    __syncthreads();

    for (int kx = 0; kx < KC; ++kx) {
      const float4 c0 = *(const float4*)&ct[kx * LDT + tb * 8];
      const float4 c1 = *(const float4*)&ct[kx * LDT + tb * 8 + 4];
      const float4 w0 = *(const float4*)&wt[kx * LDT + tv * 8];
      const float4 w1 = *(const float4*)&wt[kx * LDT + tv * 8 + 4];
      const float cw[8] = {c0.x, c0.y, c0.z, c0.w, c1.x, c1.y, c1.z, c1.w};
      const float wv[8] = {w0.x, w0.y, w0.z, w0.w, w1.x, w1.y, w1.z, w1.w};
      #pragma unroll
      for (int ib = 0; ib < 8; ++ib)
        #pragma unroll
        for (int iv = 0; iv < 8; ++iv)
          acc[ib][iv] = fmaf(cw[ib], wv[iv], acc[ib][iv]);
    }
    __syncthreads();
  }

  #pragma unroll
  for (int ib = 0; ib < 8; ++ib) {
    const size_t base = (size_t)(b0 + tb * 8 + ib) * VDIM + v0 + tv * 8;
    *(float4*)&out[base]     = make_float4(acc[ib][0], acc[ib][1], acc[ib][2], acc[ib][3]);
    *(float4*)&out[base + 4] = make_float4(acc[ib][4], acc[ib][5], acc[ib][6], acc[ib][7]);
  }
}

extern "C" void kernel_launch(void* const* d_in, const int* in_sizes, int n_in,
                              void* d_out, int out_size, void* d_ws, size_t ws_size,
                              hipStream_t stream) {
  const int*   tokens    = (const int*)d_in[0];
  const float* embed     = (const float*)d_in[1];
  const float* readout_w = (const float*)d_in[2];
  const float* diffusion = (const float*)d_in[3];
  const float* gamma_p   = (const float*)d_in[4];
  const float* beta_p    = (const float*)d_in[5];

  float*        comb = (float*)d_ws;                         // 512 KB
  unsigned int* Apk  = (unsigned int*)((char*)d_ws + 512 * 1024);  // 512 KB

  hipLaunchKernelGGL(pack_diffusion, dim3(512), dim3(256), 0, stream,
                     diffusion, Apk);
  hipLaunchKernelGGL(attractor_recurrence, dim3(NWG), dim3(DDIM), 0, stream,
                     tokens, embed, Apk, gamma_p, beta_p, comb);
  hipLaunchKernelGGL(logits_gemm, dim3(VDIM / 128, BDIM / 128), dim3(256), 0, stream,
                     comb, readout_w, (float*)d_out);
}

// Round 3
// 6531.325 us; speedup vs baseline: 1.2520x; 1.1237x over previous
//
#include <hip/hip_runtime.h>
#include <math.h>

#define DDIM 512
#define TLEN 128
#define RB   8
#define NWG  (256 / RB)        // 32 workgroups
#define VDIM 32000
#define NWAVE 8                // 512 threads / 64

typedef _Float16 f16x8 __attribute__((ext_vector_type(8)));
typedef float    f32x4 __attribute__((ext_vector_type(4)));
typedef _Float16 h2    __attribute__((ext_vector_type(2)));

#define SROW_ST 264   // dwords per f16-pair state row
#define F32_ST  520   // dwords per f32 LDS row

__device__ __forceinline__ unsigned int pkh2(float a, float b) {
  h2 v; v.x = (_Float16)a; v.y = (_Float16)b;
  return __builtin_bit_cast(unsigned int, v);
}

__device__ __forceinline__ float tanh_fast(float x) {
#if __has_builtin(__builtin_amdgcn_exp2f) && __has_builtin(__builtin_amdgcn_rcpf)
  const float e = __builtin_amdgcn_exp2f(x * 2.885390081777927f);  // 2*log2(e)
  return 1.f - 2.f * __builtin_amdgcn_rcpf(e + 1.f);
#else
  const float e = exp2f(x * 2.885390081777927f);
  return 1.f - 2.f / (e + 1.f);
#endif
}

// ---- pack diffusion into MFMA A-fragment order ------------------------------
// frag (it 0..31, kt 0..15), lane l, elem e: val = diff[it*16+(l&15)][kt*32+(l>>4)*8+e]
// stored as uint4 (8 f16) at element index (it*16+kt)*64 + l
__global__ __launch_bounds__(256) void pack_diffusion(
    const float* __restrict__ A, uint4* __restrict__ pk)
{
  const int slot = blockIdx.x * 256 + threadIdx.x;   // 0..32767
  const int l  = slot & 63;
  const int fr = slot >> 6;
  const int kt = fr & 15;
  const int it = fr >> 4;
  const float* src = A + (size_t)(it * 16 + (l & 15)) * DDIM + kt * 32 + (l >> 4) * 8;
  pk[slot] = make_uint4(pkh2(src[0], src[1]), pkh2(src[2], src[3]),
                        pkh2(src[4], src[5]), pkh2(src[6], src[7]));
}

// ---- recurrence: one WG = 8 batch rows, MFMA matvec -------------------------
__global__ __launch_bounds__(512) void attractor_recurrence(
    const int*   __restrict__ tokens,
    const float* __restrict__ embed,
    const uint4* __restrict__ Apk,
    const float* __restrict__ gamma_p,
    const float* __restrict__ beta_p,
    float*       __restrict__ comb_out)   // [256][512]
{
  const int tid   = threadIdx.x;
  const int w     = tid >> 6;
  const int l     = tid & 63;
  const int g     = l >> 4;
  const int rl    = l & 7;            // lane's r ((l&15)&7)
  const int row0  = blockIdx.x * RB;
  const int wbase = w * 64;

  __shared__ unsigned int srow[RB * SROW_ST];   // f16-pair state rows
  __shared__ float  sigl[RB * F32_ST];
  __shared__ float  fastl[RB * F32_ST];
  __shared__ float4 redc[NWAVE][RB];
  __shared__ float4 redt[NWAVE][6];
  __shared__ float4 carryl[RB];                 // {Σfast, ||fast||, ||slow||², 0}

  for (int x = tid; x < RB * SROW_ST; x += 512) srow[x] = 0u;
  for (int x = tid; x < RB * F32_ST;  x += 512) fastl[x] = 0.f;
  if (tid < RB) carryl[tid] = make_float4(0.f, 0.f, 0.f, 0.f);

  const float gamma = gamma_p[0];
  const float bss   = beta_p[0] * 0.5f;   // beta * SIGNAL_SCALE

  float fs[4][4], sl[4][4];               // state in MFMA C-layout [mt][reg]
  #pragma unroll
  for (int mt = 0; mt < 4; ++mt)
    #pragma unroll
    for (int q = 0; q < 4; ++q) { fs[mt][q] = 0.f; sl[mt][q] = 0.f; }
  float smean_lane = 0.f;                 // Σ fast (lane's r)
  float sl2_lane   = 0.f;                 // ||slow||² (lane's r)

  __syncthreads();

  for (int t = 0; t < TLEN; ++t) {
    //================ thread-per-column section (i = tid) ==================
    const int i = tid;
    float ev[RB], ctxv[RB], invfn[RB], fn2v[RB], smn[RB];
    #pragma unroll
    for (int r = 0; r < RB; ++r) {
      const int tok = tokens[(row0 + r) * TLEN + t];
      ev[r] = embed[(size_t)tok * DDIM + i];
    }
    #pragma unroll
    for (int r = 0; r < RB; ++r) {
      const float4 cy = carryl[r];
      smn[r]   = cy.x;
      invfn[r] = 1.f / (cy.y + 1e-6f);
      fn2v[r]  = cy.y * cy.y;
      ctxv[r]  = fastl[r * F32_ST + i] * invfn[r];
    }
    // fused WG reduction: per r {Σev, Σev², Σ ev·ctx}
    float red[24];
    #pragma unroll
    for (int r = 0; r < RB; ++r) {
      red[r]          = ev[r];
      red[RB + r]     = ev[r] * ev[r];
      red[2 * RB + r] = ev[r] * ctxv[r];
    }
    #pragma unroll
    for (int off = 32; off >= 1; off >>= 1)
      #pragma unroll
      for (int q = 0; q < 24; ++q)
        red[q] += __shfl_xor(red[q], off);
    __syncthreads();
    if (l == 0) {
      #pragma unroll
      for (int q6 = 0; q6 < 6; ++q6)
        redt[w][q6] = make_float4(red[q6*4], red[q6*4+1], red[q6*4+2], red[q6*4+3]);
    }
    __syncthreads();
    #pragma unroll
    for (int q = 0; q < 24; ++q) red[q] = 0.f;
    #pragma unroll
    for (int wv = 0; wv < NWAVE; ++wv)
      #pragma unroll
      for (int q6 = 0; q6 < 6; ++q6) {
        const float4 v = redt[wv][q6];
        red[q6*4]   += v.x; red[q6*4+1] += v.y;
        red[q6*4+2] += v.z; red[q6*4+3] += v.w;
      }
    // LN + signal per r
    #pragma unroll
    for (int r = 0; r < RB; ++r) {
      const float sev = red[r], sev2 = red[RB + r], sevc = red[2*RB + r];
      const float mu   = sev * (1.f / DDIM);
      float var = sev2 * (1.f / DDIM) - mu * mu;
      var = fmaxf(var, 0.f);
      const float inv  = rsqrtf(var + 1e-5f);
      const float n2y  = (float)DDIM * var / (var + 1e-5f);     // ||y||²
      const float invn = 1.f / fmaxf(sqrtf(n2y), 1e-12f);
      const float bi   = inv * invn;                            // base=(ev-mu)*bi
      const float sctx = invfn[r] * smn[r];                     // Σctx
      const float bdot = bi * (sevc - mu * sctx);               // base·ctx
      const float b2   = n2y * invn * invn;                     // ||base||²
      const float cn2  = fn2v[r] * invfn[r] * invfn[r];         // ||ctx||²
      const float sg2  = b2 + 2.f * gamma * bdot + gamma * gamma * cn2;
      const float isig = 1.f / (sqrtf(fmaxf(sg2, 0.f)) + 1e-6f);
      sigl[r * F32_ST + i] = ((ev[r] - mu) * bi + gamma * ctxv[r]) * isig;
    }
    __syncthreads();

    //================ MFMA section (wave w, lane l) ========================
    f32x4 sgf[4];
    #pragma unroll
    for (int mt = 0; mt < 4; ++mt)
      sgf[mt] = *(const f32x4*)&sigl[rl * F32_ST + wbase + mt * 16 + g * 4];

    const uint4* apw = Apk + (size_t)(w * 64) * 64 + l;

    #pragma unroll 1
    for (int k = 0; k < 4; ++k) {
      f32x4 C[4];
      #pragma unroll
      for (int mt = 0; mt < 4; ++mt) C[mt] = (f32x4){0.f, 0.f, 0.f, 0.f};

      uint4 ab[4][4];                      // 4-deep A prefetch pipeline
      #pragma unroll
      for (int p = 0; p < 4; ++p)
        #pragma unroll
        for (int mt = 0; mt < 4; ++mt)
          ab[p][mt] = apw[(size_t)(mt * 16 + p) * 64];

      #pragma unroll
      for (int kt = 0; kt < 16; ++kt) {
        const int p = kt & 3;
        const f16x8 bf = *(const f16x8*)&srow[rl * SROW_ST + kt * 16 + g * 4];
        uint4 cur[4];
        #pragma unroll
        for (int mt = 0; mt < 4; ++mt) cur[mt] = ab[p][mt];
        if (kt < 12) {
          #pragma unroll
          for (int mt = 0; mt < 4; ++mt)
            ab[p][mt] = apw[(size_t)(mt * 16 + kt + 4) * 64];
        }
        #pragma unroll
        for (int mt = 0; mt < 4; ++mt)
          C[mt] = __builtin_amdgcn_mfma_f32_16x16x32_f16(
                      __builtin_bit_cast(f16x8, cur[mt]), bf, C[mt], 0, 0, 0);
      }

      // elementwise update + fused {Σsp, Σsp², Σslow·sp} reduction
      const float meanr = smean_lane * (1.f / DDIM);
      const bool last = (k == 3);
      float sp[4][4];
      float vs = 0.f, v2 = 0.f, vx = 0.f;
      #pragma unroll
      for (int mt = 0; mt < 4; ++mt)
        #pragma unroll
        for (int q = 0; q < 4; ++q) {
          const float s  = fs[mt][q];
          const float th = tanh_fast(s - meanr);
          const float dr = C[mt][q] + 0.008f * th + bss * sgf[mt][q] - 0.1f * s;
          const float sv = fmaf(0.04f, dr, s);   // nan_to_num/clip are no-ops
          sp[mt][q] = sv;
          vs += sv; v2 += sv * sv;
          if (last) vx += sl[mt][q] * sv;
        }
      #pragma unroll
      for (int off = 8; off <= 32; off <<= 1) {
        vs += __shfl_xor(vs, off);
        v2 += __shfl_xor(v2, off);
        vx += __shfl_xor(vx, off);
      }
      __syncthreads();
      if (l < RB) redc[w][l] = make_float4(vs, v2, vx, 0.f);
      __syncthreads();
      float S = 0.f, S2 = 0.f, SX = 0.f;
      #pragma unroll
      for (int wv = 0; wv < NWAVE; ++wv) {
        const float4 v = redc[wv][rl];
        S += v.x; S2 += v.y; SX += v.z;
      }
      S *= 0.5f; S2 *= 0.5f; SX *= 0.5f;   // ×2 lane duplication (n, n+8)
      const float spn  = sqrtf(S2);
      const float ispn = 1.f / (spn + 1e-8f);
      #pragma unroll
      for (int mt = 0; mt < 4; ++mt)
        #pragma unroll
        for (int q = 0; q < 4; ++q)
          fs[mt][q] = sp[mt][q] * ispn;
      smean_lane = S * ispn;

      if ((l & 15) < RB) {                 // publish f16 state for next B-frags
        #pragma unroll
        for (int mt = 0; mt < 4; ++mt) {
          const int i0 = wbase + mt * 16 + g * 4;
          uint2 pkv;
          pkv.x = pkh2(fs[mt][0], fs[mt][1]);
          pkv.y = pkh2(fs[mt][2], fs[mt][3]);
          *(uint2*)&srow[rl * SROW_ST + (i0 >> 1)] = pkv;
        }
      }

      if (last) {
        const float fnorm = spn * ispn;                 // ||fast||
        const float sdf   = SX * ispn;                  // slow·fast
        const float sn2   = 0.9025f * sl2_lane + 0.095f * sdf
                          + 0.0025f * fnorm * fnorm;
        const float sn    = sqrtf(fmaxf(sn2, 0.f));
        const float scale = (sn > 0.5f) ? 0.5f / (sn + 1e-12f) : 1.f;
        #pragma unroll
        for (int mt = 0; mt < 4; ++mt)
          #pragma unroll
          for (int q = 0; q < 4; ++q)
            sl[mt][q] = (0.95f * sl[mt][q] + 0.05f * fs[mt][q]) * scale;
        sl2_lane = sn2 * scale * scale;
        if (w == 0 && l < RB)
          carryl[l] = make_float4(S * ispn, fnorm, sl2_lane, 0.f);
        if ((l & 15) < RB) {
          #pragma unroll
          for (int mt = 0; mt < 4; ++mt) {
            const int i0 = wbase + mt * 16 + g * 4;
            *(float4*)&fastl[rl * F32_ST + i0] =
                make_float4(fs[mt][0], fs[mt][1], fs[mt][2], fs[mt][3]);
            if (t == TLEN - 1) {
              *(float4*)&comb_out[(size_t)(row0 + rl) * DDIM + i0] =
                  make_float4(fs[mt][0] + 0.3f * sl[mt][0],
                              fs[mt][1] + 0.3f * sl[mt][1],
                              fs[mt][2] + 0.3f * sl[mt][2],
                              fs[mt][3] + 0.3f * sl[mt][3]);
            }
          }
        }
      }
      __syncthreads();
    } // conv steps
  } // tokens
}

// ---- readout GEMM: out[b][v] = Σ_d comb[b][d]·W[v][d] -----------------------
#define KC  32
#define LDT 132

__global__ __launch_bounds__(256) void logits_gemm(
    const float* __restrict__ comb,   // [256][512]
    const float* __restrict__ W,      // [32000][512]
    float*       __restrict__ out)    // [256][32000]
{
  __shared__ float wt[KC * LDT];
  __shared__ float ct[KC * LDT];

  const int tid = threadIdx.x;
  const int v0  = blockIdx.x * 128;
  const int b0  = blockIdx.y * 128;
  const int tb  = tid >> 4;
  const int tv  = tid & 15;

  float acc[8][8];
  #pragma unroll
  for (int a = 0; a < 8; ++a)
    #pragma unroll
    for (int b = 0; b < 8; ++b) acc[a][b] = 0.f;

  for (int kk = 0; kk < DDIM; kk += KC) {
    #pragma unroll
    for (int it = 0; it < 4; ++it) {
      const int l4  = tid + it * 256;
      const int row = l4 >> 3;
      const int k4  = (l4 & 7) << 2;
      const float4 gw = *(const float4*)&W[(size_t)(v0 + row) * DDIM + kk + k4];
      const float4 gc = *(const float4*)&comb[(size_t)(b0 + row) * DDIM + kk + k4];
      wt[(k4 + 0) * LDT + row] = gw.x;
      wt[(k4 + 1) * LDT + row] = gw.y;
      wt[(k4 + 2) * LDT + row] = gw.z;
      wt[(k4 + 3) * LDT + row] = gw.w;
      ct[(k4 + 0) * LDT + row] = gc.x;
      ct[(k4 + 1) * LDT + row] = gc.y;
      ct[(k4 + 2) * LDT + row] = gc.z;
      ct[(k4 + 3) * LDT + row] = gc.w;
    }
    __syncthreads();

    for (int kx = 0; kx < KC; ++kx) {
      const float4 c0 = *(const float4*)&ct[kx * LDT + tb * 8];
      const float4 c1 = *(const float4*)&ct[kx * LDT + tb * 8 + 4];
      const float4 w0 = *(const float4*)&wt[kx * LDT + tv * 8];
      const float4 w1 = *(const float4*)&wt[kx * LDT + tv * 8 + 4];
      const float cw[8] = {c0.x, c0.y, c0.z, c0.w, c1.x, c1.y, c1.z, c1.w};
      const float wv[8] = {w0.x, w0.y, w0.z, w0.w, w1.x, w1.y, w1.z, w1.w};
      #pragma unroll
      for (int ib = 0; ib < 8; ++ib)
        #pragma unroll
        for (int iv = 0; iv < 8; ++iv)
          acc[ib][iv] = fmaf(cw[ib], wv[iv], acc[ib][iv]);
    }
    __syncthreads();
  }

  #pragma unroll
  for (int ib = 0; ib < 8; ++ib) {
    const size_t base = (size_t)(b0 + tb * 8 + ib) * VDIM + v0 + tv * 8;
    *(float4*)&out[base]     = make_float4(acc[ib][0], acc[ib][1], acc[ib][2], acc[ib][3]);
    *(float4*)&out[base + 4] = make_float4(acc[ib][4], acc[ib][5], acc[ib][6], acc[ib][7]);
  }
}

extern "C" void kernel_launch(void* const* d_in, const int* in_sizes, int n_in,
                              void* d_out, int out_size, void* d_ws, size_t ws_size,
                              hipStream_t stream) {
  const int*   tokens    = (const int*)d_in[0];
  const float* embed     = (const float*)d_in[1];
  const float* readout_w = (const float*)d_in[2];
  const float* diffusion = (const float*)d_in[3];
  const float* gamma_p   = (const float*)d_in[4];
  const float* beta_p    = (const float*)d_in[5];

  float* comb = (float*)d_ws;                              // 512 KB
  uint4* Apk  = (uint4*)((char*)d_ws + 512 * 1024);        // 512 KB

  hipLaunchKernelGGL(pack_diffusion, dim3(128), dim3(256), 0, stream,
                     diffusion, Apk);
  hipLaunchKernelGGL(attractor_recurrence, dim3(NWG), dim3(512), 0, stream,
                     tokens, embed, Apk, gamma_p, beta_p, comb);
  hipLaunchKernelGGL(logits_gemm, dim3(VDIM / 128, 256 / 128), dim3(256), 0, stream,
                     comb, readout_w, (float*)d_out);
}